// Round 1
// baseline (852.219 us; speedup 1.0000x reference)
//
#include <hip/hip_runtime.h>

// Problem dims (fixed by reference)
#define BB 32
#define HH 3
#define MM 2048
#define DD 512
#define LL 32
#define TT 2049
#define NCHUNK 32          // m-chunks per (b,hop); partials fit prior ws footprint
#define MCHUNK (MM / NCHUNK)   // 64 m per block, 16 per wave

// ---------------------------------------------------------------------------
// k1: u[b,d] = sum_l B_emb[query[b,l], d] * pos_enc[l, d]
// grid: BB blocks x 256 threads, each thread handles 2 consecutive d
// ---------------------------------------------------------------------------
__global__ __launch_bounds__(256) void qembed_kernel(
    const int* __restrict__ query, const float* __restrict__ B_emb,
    const float* __restrict__ pos_enc, float* __restrict__ u) {
    int b = blockIdx.x;
    int d0 = threadIdx.x * 2;
    float a0 = 0.f, a1 = 0.f;
#pragma unroll 4
    for (int l = 0; l < LL; ++l) {
        int q = query[b * LL + l];
        float2 e = *(const float2*)(B_emb + (size_t)q * DD + d0);
        float2 pe = *(const float2*)(pos_enc + l * DD + d0);
        a0 += e.x * pe.x;
        a1 += e.y * pe.y;
    }
    u[b * DD + d0] = a0;
    u[b * DD + d0 + 1] = a1;
}

// ---------------------------------------------------------------------------
// k2 (fused hop): flash-style online softmax-weighted sum over an m-chunk.
// For each m in the chunk:
//   logit = dot(key_mems[b,hop,m,:] + TA[hop,t,:], u[b,:])
//   online: rescale running (sum, acc) by exp(old_max-new_max),
//           acc += exp(logit-new_max) * (val_mems[b,hop,m,:] + TC[hop,t,:])
// Per-block output: pmx[c,b] = chunk max, ps[c,b] = chunk sum (rel. to max),
//                   partials[c,b,:] = chunk weighted acc (rel. to max).
// grid: (NCHUNK, BB) x 256 threads = 4 waves; wave w owns m = base+4j+w.
// Lane covers 8 consecutive d (two float4 per stream). key/val stream from
// HBM in the same pass; TA/TC gathers are L2/L3-resident.
// ---------------------------------------------------------------------------
__global__ __launch_bounds__(256) void fused_hop_kernel(
    const float* __restrict__ key_mems, const float* __restrict__ val_mems,
    const float* __restrict__ TA, const float* __restrict__ TC,
    const int* __restrict__ rel_time, const float* __restrict__ u,
    float* __restrict__ partials, float* __restrict__ pmx,
    float* __restrict__ ps, int hop) {
    __shared__ float sm[4][DD];
    __shared__ float smx[4];
    __shared__ float ssum[4];
    int b = blockIdx.y, c = blockIdx.x;
    int wave = threadIdx.x >> 6, lane = threadIdx.x & 63;
    int d0 = lane * 8;

    // u slice lives in registers for the whole chunk
    float4 u0 = *(const float4*)(u + b * DD + d0);
    float4 u1 = *(const float4*)(u + b * DD + d0 + 4);

    const size_t kbase = (size_t)(b * HH + hop) * MM * DD;

    float rmax = -3.4e38f, rsum = 0.f;
    float acc[8] = {0.f, 0.f, 0.f, 0.f, 0.f, 0.f, 0.f, 0.f};

#pragma unroll 2
    for (int j = 0; j < MCHUNK / 4; ++j) {
        int m = c * MCHUNK + j * 4 + wave;
        int t = rel_time[b * MM + m];
        const float* krow = key_mems + kbase + (size_t)m * DD + d0;
        const float* vrow = val_mems + kbase + (size_t)m * DD + d0;
        const float* arow = TA + (size_t)(hop * TT + t) * DD + d0;
        const float* crow = TC + (size_t)(hop * TT + t) * DD + d0;

        float4 k0 = *(const float4*)krow;
        float4 k1 = *(const float4*)(krow + 4);
        float4 a0 = *(const float4*)arow;
        float4 a1 = *(const float4*)(arow + 4);
        float4 v0 = *(const float4*)vrow;
        float4 v1 = *(const float4*)(vrow + 4);
        float4 c0 = *(const float4*)crow;
        float4 c1 = *(const float4*)(crow + 4);

        float dp = (k0.x + a0.x) * u0.x + (k0.y + a0.y) * u0.y +
                   (k0.z + a0.z) * u0.z + (k0.w + a0.w) * u0.w +
                   (k1.x + a1.x) * u1.x + (k1.y + a1.y) * u1.y +
                   (k1.z + a1.z) * u1.z + (k1.w + a1.w) * u1.w;
#pragma unroll
        for (int off = 32; off > 0; off >>= 1) dp += __shfl_xor(dp, off);

        // online softmax update (wave-uniform: dp identical on all lanes)
        float nm = fmaxf(rmax, dp);
        float scale = expf(rmax - nm);   // 0 on first iter (-3.4e38 - dp -> -inf)
        float w = expf(dp - nm);
        rsum = rsum * scale + w;
        acc[0] = acc[0] * scale + w * (v0.x + c0.x);
        acc[1] = acc[1] * scale + w * (v0.y + c0.y);
        acc[2] = acc[2] * scale + w * (v0.z + c0.z);
        acc[3] = acc[3] * scale + w * (v0.w + c0.w);
        acc[4] = acc[4] * scale + w * (v1.x + c1.x);
        acc[5] = acc[5] * scale + w * (v1.y + c1.y);
        acc[6] = acc[6] * scale + w * (v1.z + c1.z);
        acc[7] = acc[7] * scale + w * (v1.w + c1.w);
        rmax = nm;
    }

    if (lane == 0) {
        smx[wave] = rmax;
        ssum[wave] = rsum;
    }
    *(float4*)&sm[wave][d0] = make_float4(acc[0], acc[1], acc[2], acc[3]);
    *(float4*)&sm[wave][d0 + 4] = make_float4(acc[4], acc[5], acc[6], acc[7]);
    __syncthreads();

    float bmx = fmaxf(fmaxf(smx[0], smx[1]), fmaxf(smx[2], smx[3]));
    float e0 = expf(smx[0] - bmx);
    float e1 = expf(smx[1] - bmx);
    float e2 = expf(smx[2] - bmx);
    float e3 = expf(smx[3] - bmx);

    if (threadIdx.x == 0) {
        pmx[c * BB + b] = bmx;
        ps[c * BB + b] = ssum[0] * e0 + ssum[1] * e1 + ssum[2] * e2 + ssum[3] * e3;
    }
    int d = threadIdx.x * 2;
    float2 po;
    po.x = sm[0][d] * e0 + sm[1][d] * e1 + sm[2][d] * e2 + sm[3][d] * e3;
    po.y = sm[0][d + 1] * e0 + sm[1][d + 1] * e1 + sm[2][d + 1] * e2 +
           sm[3][d + 1] * e3;
    *(float2*)(partials + ((size_t)c * BB + b) * DD + d) = po;
}

// ---------------------------------------------------------------------------
// k3 (combine): cross-chunk flash combine + recurrent update.
//   MX = max_c pmx[c,b]; S = sum_c ps[c,b]*exp(pmx-MX)
//   u[b,d] += (sum_c partials[c,b,d]*exp(pmx-MX)) / S
// grid: BB blocks x 256 threads (2 d per thread). On last hop also writes out.
// ---------------------------------------------------------------------------
__global__ __launch_bounds__(256) void combine_kernel(
    const float* __restrict__ partials, const float* __restrict__ pmx,
    const float* __restrict__ ps, float* __restrict__ u,
    float* __restrict__ out, int write_out) {
    __shared__ float sscale[NCHUNK];
    int b = blockIdx.x;
    int tid = threadIdx.x;

    float MX = -3.4e38f;
#pragma unroll
    for (int cc = 0; cc < NCHUNK; ++cc) MX = fmaxf(MX, pmx[cc * BB + b]);
    if (tid < NCHUNK) sscale[tid] = expf(pmx[tid * BB + b] - MX);
    __syncthreads();

    float S = 0.f;
#pragma unroll
    for (int cc = 0; cc < NCHUNK; ++cc) S += ps[cc * BB + b] * sscale[cc];
    float inv = 1.f / S;

    int d = tid * 2;
    float ox = 0.f, oy = 0.f;
#pragma unroll 4
    for (int cc = 0; cc < NCHUNK; ++cc) {
        float2 pv = *(const float2*)(partials + ((size_t)cc * BB + b) * DD + d);
        float sc = sscale[cc];
        ox += pv.x * sc;
        oy += pv.y * sc;
    }
    float2 uu = *(const float2*)(u + b * DD + d);
    uu.x += ox * inv;
    uu.y += oy * inv;
    *(float2*)(u + b * DD + d) = uu;
    if (write_out) *(float2*)(out + b * DD + d) = uu;
}

extern "C" void kernel_launch(void* const* d_in, const int* in_sizes, int n_in,
                              void* d_out, int out_size, void* d_ws, size_t ws_size,
                              hipStream_t stream) {
    const int* query = (const int*)d_in[0];
    const int* rel_time = (const int*)d_in[1];
    const float* key_mems = (const float*)d_in[2];
    const float* val_mems = (const float*)d_in[3];
    const float* B_emb = (const float*)d_in[4];
    const float* TA = (const float*)d_in[5];
    const float* TC = (const float*)d_in[6];
    const float* pos_enc = (const float*)d_in[7];
    float* out = (float*)d_out;

    float* ws = (float*)d_ws;
    float* u = ws;                               // B*D           = 16384 floats
    float* pmx = u + BB * DD;                    // NCHUNK*B      = 1024
    float* ps = pmx + NCHUNK * BB;               // NCHUNK*B      = 1024
    float* partials = ps + NCHUNK * BB;          // NCHUNK*B*D    = 524288

    qembed_kernel<<<BB, 256, 0, stream>>>(query, B_emb, pos_enc, u);

    for (int hop = 0; hop < HH; ++hop) {
        fused_hop_kernel<<<dim3(NCHUNK, BB), 256, 0, stream>>>(
            key_mems, val_mems, TA, TC, rel_time, u, partials, pmx, ps, hop);
        combine_kernel<<<BB, 256, 0, stream>>>(partials, pmx, ps, u, out,
                                               hop == HH - 1 ? 1 : 0);
    }
}